// Round 4
// baseline (1135.941 us; speedup 1.0000x reference)
//
#include <hip/hip_runtime.h>
#include <math.h>

// Problem constants
#define TT    48
#define BB    96
#define DG    192
#define DH    384
#define NSTEP 47     // T-1 scan steps
#define SETI  3      // inner settling iterations
#define HP    392    // padded hist row stride (floats): +8 banks breaks conflicts

// fast-kernel config
#define NT_F  512
#define NW_F  8      // waves
#define NOW_F 6      // owner waves (tid < DH)
#define NG_F  32     // 16-lane groups

// fallback (round-3) config
#define NT_O  768
#define NW_O  12
#define NOW_O 6
#define NG_O  48

typedef unsigned short ushort_t;

__device__ __forceinline__ float group16_reduce(float v) {
  v += __shfl_xor(v, 8, 64);
  v += __shfl_xor(v, 4, 64);
  v += __shfl_xor(v, 2, 64);
  v += __shfl_xor(v, 1, 64);
  return v;
}

__device__ __forceinline__ float blo(unsigned u) {
  return __uint_as_float(u << 16);
}
__device__ __forceinline__ float bhi(unsigned u) {
  return __uint_as_float(u & 0xFFFF0000u);
}

// ====================== FAST PATH ======================
// Recurrent kernel with W_h resident in VGPRs (bf16) and W_g*z+b precomputed.
__global__ __launch_bounds__(NT_F) void fw_rnn_fast(
    const float* __restrict__ XZ,       // [T*B, DH] = W_g z + b_h
    const ushort_t* __restrict__ Whb,   // [DH, DH] bf16
    const float* __restrict__ ln_g,
    const float* __restrict__ ln_b,
    const float* __restrict__ alpha_fw,
    float* __restrict__ out)            // [B, DH]
{
  __shared__ float hist[NSTEP * HP];
  __shared__ float hs[DH];
  __shared__ float hbs[DH];
  __shared__ float xzs[DH];
  __shared__ float wlam[NSTEP + 1];
  __shared__ float carr[NSTEP + 1];
  __shared__ float redA[NW_F * 2];
  __shared__ float redB[2][NOW_F * 5];

  const int tid    = threadIdx.x;
  const int b      = blockIdx.x;
  const int lane   = tid & 63, wv = tid >> 6;
  const int g      = tid >> 4, lane16 = tid & 15;
  const bool owner = (tid < DH);

  // ---- preload W_h rows into registers: group g owns rows r = p*32+g ----
  uint2 Wreg[12][6];
#pragma unroll
  for (int p = 0; p < 12; ++p) {
    const uint2* wrow = (const uint2*)(Whb + (size_t)(p * NG_F + g) * DH);
#pragma unroll
    for (int c = 0; c < 6; ++c) Wreg[p][c] = wrow[lane16 + 16 * c];
  }

  float g_i = 0.f, be_i = 0.f;
  if (owner) { g_i = ln_g[tid]; be_i = ln_b[tid]; }
  const float af   = alpha_fw[0];
  const float kcur = (af >= 0.f) ? (1.f + log1pf(expf(af)))
                                 : (1.f / (1.f + log1pf(expf(-af))));
  const float invD = 1.0f / (float)DH;

  // stage XZ row for t=0
  if (tid < DH / 4)
    ((float4*)xzs)[tid] = ((const float4*)(XZ + (size_t)b * DH))[tid];
  __syncthreads();

  float Shb = 0.f, Shb2 = 0.f;

  for (int t = 0; t < NSTEP; ++t) {
    // ---------- base phase: h_base = W_h h_{t-1} + xzs, fused LN stats ----
    float s1 = 0.f, s2 = 0.f;
    if (t > 0) {
      float4 h[6];
      const float4* h4 = (const float4*)(hist + (size_t)(t - 1) * HP);
#pragma unroll
      for (int c = 0; c < 6; ++c) h[c] = h4[lane16 + 16 * c];
#pragma unroll
      for (int p = 0; p < 12; ++p) {
        float acc = 0.f;
#pragma unroll
        for (int c = 0; c < 6; ++c) {
          uint2 w = Wreg[p][c];
          acc = fmaf(blo(w.x), h[c].x, acc);
          acc = fmaf(bhi(w.x), h[c].y, acc);
          acc = fmaf(blo(w.y), h[c].z, acc);
          acc = fmaf(bhi(w.y), h[c].w, acc);
        }
        acc = group16_reduce(acc);
        if (lane16 == 0) {
          const int r = p * NG_F + g;
          float v = acc + xzs[r];
          hbs[r] = v;
          s1 += v;
          s2 += v * v;
        }
      }
    } else if (owner) {
      float v = xzs[tid];
      s1 = v;
      s2 = v * v;
    }
    {
      float v0 = s1, v1 = s2;
#pragma unroll
      for (int off = 32; off; off >>= 1) {
        v0 += __shfl_xor(v0, off, 64);
        v1 += __shfl_xor(v1, off, 64);
      }
      if (lane == 0) { redA[wv * 2] = v0; redA[wv * 2 + 1] = v1; }
    }
    __syncthreads();  // (a): hbs + redA visible

    float hb = 0.f, hsv = 0.f;
    {
      float S1 = 0.f, S2 = 0.f;
#pragma unroll
      for (int w = 0; w < NW_F; ++w) { S1 += redA[w * 2]; S2 += redA[w * 2 + 1]; }
      Shb = S1; Shb2 = S2;
      if (owner) {
        hb = (t > 0) ? hbs[tid] : xzs[tid];
        float m   = S1 * invD;
        float var = S2 * invD - m * m;
        hsv = fmaxf((hb - m) * rsqrtf(var + 1e-5f) * g_i + be_i, 0.f);
        hs[tid] = hsv;
      }
    }
    if (t == 0) {
      if (owner) hist[tid] = hsv;
      if (tid == 0) wlam[0] = 0.5f;
      if (tid >= DH && tid < DH + DH / 4)
        ((float4*)xzs)[tid - DH] =
            ((const float4*)(XZ + ((size_t)BB + b) * DH))[tid - DH];
      __syncthreads();
      continue;
    }
    __syncthreads();  // (b): hs visible

    // ---------- settling ----------
    for (int s = 0; s < SETI; ++s) {
      float4 sv[6];
#pragma unroll
      for (int c = 0; c < 6; ++c) sv[c] = ((const float4*)hs)[lane16 + 16 * c];
      for (int tau = g; tau < t; tau += NG_F) {
        const float4* hh = (const float4*)(hist + (size_t)tau * HP);
        float p_ = 0.f;
#pragma unroll
        for (int c = 0; c < 6; ++c) {
          float4 x = hh[lane16 + 16 * c];
          p_ = fmaf(x.x, sv[c].x, p_); p_ = fmaf(x.y, sv[c].y, p_);
          p_ = fmaf(x.z, sv[c].z, p_); p_ = fmaf(x.w, sv[c].w, p_);
        }
        p_ = group16_reduce(p_);
        if (lane16 == 0) carr[tau] = p_ * wlam[tau];
      }
      __syncthreads();  // (i): carr visible

      float ah = 0.f;
      if (owner) {
        for (int tau = 0; tau < t; ++tau)
          ah = fmaf(carr[tau], hist[(size_t)tau * HP + tid], ah);
        float v0 = hsv * ah, v1 = hsv * hsv, v2 = ah * ah, v3 = hb * ah, v4 = ah;
#pragma unroll
        for (int off = 32; off; off >>= 1) {
          v0 += __shfl_xor(v0, off, 64);
          v1 += __shfl_xor(v1, off, 64);
          v2 += __shfl_xor(v2, off, 64);
          v3 += __shfl_xor(v3, off, 64);
          v4 += __shfl_xor(v4, off, 64);
        }
        if (lane == 0) {
          float* rb = redB[s & 1];
          rb[wv * 5 + 0] = v0; rb[wv * 5 + 1] = v1; rb[wv * 5 + 2] = v2;
          rb[wv * 5 + 3] = v3; rb[wv * 5 + 4] = v4;
        }
      }
      __syncthreads();  // (ii): redB visible

      if (owner) {
        const float* rb = redB[s & 1];
        float S0 = 0, S1 = 0, S2 = 0, S3 = 0, S4 = 0;
#pragma unroll
        for (int w = 0; w < NOW_F; ++w) {
          S0 += rb[w * 5 + 0]; S1 += rb[w * 5 + 1]; S2 += rb[w * 5 + 2];
          S3 += rb[w * 5 + 3]; S4 += rb[w * 5 + 4];
        }
        float n1 = fmaxf(sqrtf(S1), 1e-6f);
        float n2 = fmaxf(sqrtf(S2), 1e-6f);
        float R  = fminf(fmaxf(S0 / (n1 * n2), 0.f), 1.f);
        float a  = 1.f - powf(1.f - R, kcur);
        float beta = 1.f - a * a;
        float mu  = (beta * Shb + a * S4) * invD;
        float Exx = (beta * beta * Shb2 + 2.f * beta * a * S3 + a * a * S2) * invD;
        float var = Exx - mu * mu;
        float xv  = beta * hb + a * ah;
        hsv = fmaxf((xv - mu) * rsqrtf(var + 1e-5f) * g_i + be_i, 0.f);
        hs[tid] = hsv;
        if (s == SETI - 1) hist[(size_t)t * HP + tid] = hsv;
      }
      if (s == SETI - 1) {
        if (tid < t) wlam[tid] *= 0.9f;
        else if (tid == t) wlam[tid] = 0.5f;
        if (tid >= DH && tid < DH + DH / 4)
          ((float4*)xzs)[tid - DH] =
              ((const float4*)(XZ + ((size_t)(t + 1) * BB + b) * DH))[tid - DH];
      }
      __syncthreads();  // (iii)
    }
  }

  // ================= final (query) step =================
  {
    float s1 = 0.f, s2 = 0.f;
    {
      float4 h[6];
      const float4* h4 = (const float4*)(hist + (size_t)(NSTEP - 1) * HP);
#pragma unroll
      for (int c = 0; c < 6; ++c) h[c] = h4[lane16 + 16 * c];
#pragma unroll
      for (int p = 0; p < 12; ++p) {
        float acc = 0.f;
#pragma unroll
        for (int c = 0; c < 6; ++c) {
          uint2 w = Wreg[p][c];
          acc = fmaf(blo(w.x), h[c].x, acc);
          acc = fmaf(bhi(w.x), h[c].y, acc);
          acc = fmaf(blo(w.y), h[c].z, acc);
          acc = fmaf(bhi(w.y), h[c].w, acc);
        }
        acc = group16_reduce(acc);
        if (lane16 == 0) {
          const int r = p * NG_F + g;
          float v = acc + xzs[r];
          hbs[r] = v;
          s1 += v;
          s2 += v * v;
        }
      }
    }
    {
      float v0 = s1, v1 = s2;
#pragma unroll
      for (int off = 32; off; off >>= 1) {
        v0 += __shfl_xor(v0, off, 64);
        v1 += __shfl_xor(v1, off, 64);
      }
      if (lane == 0) { redA[wv * 2] = v0; redA[wv * 2 + 1] = v1; }
    }
    __syncthreads();

    float hb = 0.f, hv = 0.f;
    {
      float S1 = 0.f, S2 = 0.f;
#pragma unroll
      for (int w = 0; w < NW_F; ++w) { S1 += redA[w * 2]; S2 += redA[w * 2 + 1]; }
      Shb = S1; Shb2 = S2;
      if (owner) {
        hb = hbs[tid];
        float m   = S1 * invD;
        float var = S2 * invD - m * m;
        hv = fmaxf((hb - m) * rsqrtf(var + 1e-5f) * g_i + be_i, 0.f);
        hs[tid] = hv;
      }
    }
    __syncthreads();

    for (int s = 0; s < SETI; ++s) {
      float4 sv[6];
#pragma unroll
      for (int c = 0; c < 6; ++c) sv[c] = ((const float4*)hs)[lane16 + 16 * c];
      for (int tau = g; tau < NSTEP; tau += NG_F) {
        const float4* hh = (const float4*)(hist + (size_t)tau * HP);
        float p_ = 0.f;
#pragma unroll
        for (int c = 0; c < 6; ++c) {
          float4 x = hh[lane16 + 16 * c];
          p_ = fmaf(x.x, sv[c].x, p_); p_ = fmaf(x.y, sv[c].y, p_);
          p_ = fmaf(x.z, sv[c].z, p_); p_ = fmaf(x.w, sv[c].w, p_);
        }
        p_ = group16_reduce(p_);
        if (lane16 == 0) carr[tau] = p_ * wlam[tau];
      }
      __syncthreads();

      float ah = 0.f;
      if (owner) {
        for (int tau = 0; tau < NSTEP; ++tau)
          ah = fmaf(carr[tau], hist[(size_t)tau * HP + tid], ah);
        float v0 = ah, v1 = ah * ah, v2 = hb * ah;
#pragma unroll
        for (int off = 32; off; off >>= 1) {
          v0 += __shfl_xor(v0, off, 64);
          v1 += __shfl_xor(v1, off, 64);
          v2 += __shfl_xor(v2, off, 64);
        }
        if (lane == 0) {
          float* rb = redB[s & 1];
          rb[wv * 5 + 0] = v0; rb[wv * 5 + 1] = v1; rb[wv * 5 + 2] = v2;
        }
      }
      __syncthreads();

      if (owner) {
        const float* rb = redB[s & 1];
        float S0 = 0, S1 = 0, S2 = 0;
#pragma unroll
        for (int w = 0; w < NOW_F; ++w) {
          S0 += rb[w * 5 + 0]; S1 += rb[w * 5 + 1]; S2 += rb[w * 5 + 2];
        }
        float Sx  = Shb + S0;
        float Sxx = Shb2 + 2.f * S2 + S1;
        float mu  = Sx * invD;
        float var = Sxx * invD - mu * mu;
        float xv  = hb + ah;
        hv = fmaxf((xv - mu) * rsqrtf(var + 1e-5f) * g_i + be_i, 0.f);
        if (s < SETI - 1) hs[tid] = hv;
      }
      if (s < SETI - 1) __syncthreads();
    }

    if (owner) out[(size_t)b * DH + tid] = hv;
  }
}

// XZ[t,b,:] = W_g z[t,b] + b_h  — fully parallel precompute (fp32 W_g).
// Block = (t, b-tile of 8). 512 threads, 32 groups x 12 rows.
__global__ __launch_bounds__(NT_F) void xz_kernel(
    const float* __restrict__ z_seq, const float* __restrict__ W_g,
    const float* __restrict__ b_h, float* __restrict__ XZ)
{
  __shared__ float zs[8 * DG];
  const int tid = threadIdx.x;
  const int t = blockIdx.x, b0 = blockIdx.y * 8;
  const int g = tid >> 4, lane16 = tid & 15;

  const float4* src = (const float4*)(z_seq + ((size_t)t * BB + b0) * DG);
  if (tid < 8 * DG / 4) ((float4*)zs)[tid] = src[tid];
  __syncthreads();

#pragma unroll 2
  for (int p = 0; p < 12; ++p) {
    const int r = p * NG_F + g;
    const float4* wr = (const float4*)(W_g + (size_t)r * DG);
    float4 w[3];
#pragma unroll
    for (int c = 0; c < 3; ++c) w[c] = wr[lane16 + 16 * c];
    float acc[8];
#pragma unroll
    for (int bb = 0; bb < 8; ++bb) acc[bb] = 0.f;
#pragma unroll
    for (int bb = 0; bb < 8; ++bb) {
      const float4* zz = (const float4*)(zs + bb * DG);
#pragma unroll
      for (int c = 0; c < 3; ++c) {
        float4 z = zz[lane16 + 16 * c];
        acc[bb] = fmaf(w[c].x, z.x, acc[bb]);
        acc[bb] = fmaf(w[c].y, z.y, acc[bb]);
        acc[bb] = fmaf(w[c].z, z.z, acc[bb]);
        acc[bb] = fmaf(w[c].w, z.w, acc[bb]);
      }
    }
#pragma unroll
    for (int bb = 0; bb < 8; ++bb) acc[bb] = group16_reduce(acc[bb]);
    if (lane16 == 0) {
      float bh = b_h[r];
#pragma unroll
      for (int bb = 0; bb < 8; ++bb)
        XZ[((size_t)t * BB + b0 + bb) * DH + r] = acc[bb] + bh;
    }
  }
}

// fp32 -> bf16 (RTN-even)
__global__ void cvt_kernel(const float* __restrict__ src,
                           ushort_t* __restrict__ dst, int n) {
  int i = blockIdx.x * blockDim.x + threadIdx.x;
  if (i < n) {
    unsigned u = __float_as_uint(src[i]);
    unsigned r = (u + 0x7FFFu + ((u >> 16) & 1u)) >> 16;
    dst[i] = (ushort_t)r;
  }
}

// ====================== FALLBACK (round-3) ======================
template <bool BF16W>
__device__ __forceinline__ void matvec_o(
    const float* __restrict__ Wh_f, const float* __restrict__ Wg_f,
    const ushort_t* __restrict__ Wh_b, const ushort_t* __restrict__ Wg_b,
    const float* __restrict__ hprev, const float* __restrict__ zsh,
    const float (&bias)[8], float* __restrict__ hbs,
    float& s1, float& s2, int g, int lane16, bool with_h)
{
  const float4* z4 = (const float4*)zsh;
  const float4* h4 = (const float4*)hprev;
#pragma unroll 2
  for (int p = 0; p < 8; ++p) {
    const int r = p * NG_O + g;
    float acc = 0.f;
    if (BF16W) {
      const uint2* wg = (const uint2*)Wg_b + (size_t)r * (DG / 4);
#pragma unroll
      for (int c = 0; c < 3; ++c) {
        uint2 u = wg[lane16 + 16 * c];
        float4 z = z4[lane16 + 16 * c];
        acc = fmaf(blo(u.x), z.x, acc); acc = fmaf(bhi(u.x), z.y, acc);
        acc = fmaf(blo(u.y), z.z, acc); acc = fmaf(bhi(u.y), z.w, acc);
      }
      if (with_h) {
        const uint4* wh = (const uint4*)Wh_b + (size_t)r * (DH / 8);
#pragma unroll
        for (int c = 0; c < 3; ++c) {
          uint4 u = wh[lane16 + 16 * c];
          float4 ha = h4[(lane16 + 16 * c) * 2];
          float4 hb2 = h4[(lane16 + 16 * c) * 2 + 1];
          acc = fmaf(blo(u.x), ha.x, acc);  acc = fmaf(bhi(u.x), ha.y, acc);
          acc = fmaf(blo(u.y), ha.z, acc);  acc = fmaf(bhi(u.y), ha.w, acc);
          acc = fmaf(blo(u.z), hb2.x, acc); acc = fmaf(bhi(u.z), hb2.y, acc);
          acc = fmaf(blo(u.w), hb2.z, acc); acc = fmaf(bhi(u.w), hb2.w, acc);
        }
      }
    } else {
      const float4* wg = (const float4*)Wg_f + (size_t)r * (DG / 4);
#pragma unroll
      for (int c = 0; c < 3; ++c) {
        float4 w = wg[lane16 + 16 * c], z = z4[lane16 + 16 * c];
        acc = fmaf(w.x, z.x, acc); acc = fmaf(w.y, z.y, acc);
        acc = fmaf(w.z, z.z, acc); acc = fmaf(w.w, z.w, acc);
      }
      if (with_h) {
        const float4* wh = (const float4*)Wh_f + (size_t)r * (DH / 4);
#pragma unroll
        for (int c = 0; c < 6; ++c) {
          float4 w = wh[lane16 + 16 * c], h = h4[lane16 + 16 * c];
          acc = fmaf(w.x, h.x, acc); acc = fmaf(w.y, h.y, acc);
          acc = fmaf(w.z, h.z, acc); acc = fmaf(w.w, h.w, acc);
        }
      }
    }
    acc = group16_reduce(acc);
    if (lane16 == 0) {
      float vv = acc + bias[p];
      hbs[r] = vv;
      s1 += vv;
      s2 += vv * vv;
    }
  }
}

template <bool BF16W>
__global__ __launch_bounds__(NT_O) void fw_rnn_old(
    const float* __restrict__ z_seq, const float* __restrict__ Wh_f,
    const float* __restrict__ Wg_f, const ushort_t* __restrict__ Wh_b,
    const ushort_t* __restrict__ Wg_b, const float* __restrict__ b_h,
    const float* __restrict__ ln_g, const float* __restrict__ ln_b,
    const float* __restrict__ alpha_fw, float* __restrict__ out)
{
  __shared__ float hist[NSTEP * DH];
  __shared__ float hs[DH];
  __shared__ float zsh[DG];
  __shared__ float hbs[DH];
  __shared__ float wlam[NSTEP];
  __shared__ float carr[NG_O];
  __shared__ float redA[NW_O * 2];
  __shared__ float redB[2][NOW_O * 5];

  const int tid = threadIdx.x;
  const int b = blockIdx.x;
  const int lane = tid & 63, wv = tid >> 6;
  const int g = tid >> 4, lane16 = tid & 15;
  const bool owner = (tid < DH);

  float bias[8];
#pragma unroll
  for (int p = 0; p < 8; ++p) bias[p] = 0.f;
  if (lane16 == 0) {
#pragma unroll
    for (int p = 0; p < 8; ++p) bias[p] = b_h[p * NG_O + g];
  }
  float g_i = 0.f, be_i = 0.f;
  if (owner) { g_i = ln_g[tid]; be_i = ln_b[tid]; }

  const float af = alpha_fw[0];
  const float kcur = (af >= 0.f) ? (1.f + log1pf(expf(af)))
                                 : (1.f / (1.f + log1pf(expf(-af))));
  const float invD = 1.0f / (float)DH;

  if (tid < DG / 4)
    ((float4*)zsh)[tid] = ((const float4*)(z_seq + (size_t)b * DG))[tid];
  __syncthreads();

  float Shb = 0.f, Shb2 = 0.f;

  for (int t = 0; t < NSTEP; ++t) {
    float s1 = 0.f, s2 = 0.f;
    matvec_o<BF16W>(Wh_f, Wg_f, Wh_b, Wg_b,
                    hist + (size_t)(t > 0 ? t - 1 : 0) * DH, zsh, bias, hbs,
                    s1, s2, g, lane16, t > 0);
    {
      float v0 = s1, v1 = s2;
#pragma unroll
      for (int off = 32; off; off >>= 1) {
        v0 += __shfl_xor(v0, off, 64);
        v1 += __shfl_xor(v1, off, 64);
      }
      if (lane == 0) { redA[wv * 2] = v0; redA[wv * 2 + 1] = v1; }
    }
    __syncthreads();

    float hb = 0.f, hsv = 0.f;
    {
      float S1 = 0.f, S2 = 0.f;
#pragma unroll
      for (int w = 0; w < NW_O; ++w) { S1 += redA[w * 2]; S2 += redA[w * 2 + 1]; }
      Shb = S1; Shb2 = S2;
      if (owner) {
        hb = hbs[tid];
        float m = S1 * invD;
        float var = S2 * invD - m * m;
        hsv = fmaxf((hb - m) * rsqrtf(var + 1e-5f) * g_i + be_i, 0.f);
        hs[tid] = hsv;
      }
    }
    if (t == 0) {
      if (owner) hist[tid] = hsv;
      if (tid == 0) wlam[0] = 0.5f;
      if (tid >= DH && tid < DH + DG / 4)
        ((float4*)zsh)[tid - DH] =
            ((const float4*)(z_seq + ((size_t)1 * BB + b) * DG))[tid - DH];
      __syncthreads();
      continue;
    }
    __syncthreads();

    for (int s = 0; s < SETI; ++s) {
      if (g < t) {
        const float4* h4 = (const float4*)(hist + (size_t)g * DH);
        const float4* s4 = (const float4*)hs;
        float p = 0.f;
#pragma unroll
        for (int kk = 0; kk < 6; ++kk) {
          float4 hh = h4[lane16 + 16 * kk], ss = s4[lane16 + 16 * kk];
          p = fmaf(hh.x, ss.x, p); p = fmaf(hh.y, ss.y, p);
          p = fmaf(hh.z, ss.z, p); p = fmaf(hh.w, ss.w, p);
        }
        p = group16_reduce(p);
        if (lane16 == 0) carr[g] = p * wlam[g];
      }
      __syncthreads();

      float ah = 0.f;
      if (owner) {
        for (int tau = 0; tau < t; ++tau)
          ah = fmaf(carr[tau], hist[(size_t)tau * DH + tid], ah);
        float v0 = hsv * ah, v1 = hsv * hsv, v2 = ah * ah, v3 = hb * ah, v4 = ah;
#pragma unroll
        for (int off = 32; off; off >>= 1) {
          v0 += __shfl_xor(v0, off, 64);
          v1 += __shfl_xor(v1, off, 64);
          v2 += __shfl_xor(v2, off, 64);
          v3 += __shfl_xor(v3, off, 64);
          v4 += __shfl_xor(v4, off, 64);
        }
        if (lane == 0) {
          float* rb = redB[s & 1];
          rb[wv * 5 + 0] = v0; rb[wv * 5 + 1] = v1; rb[wv * 5 + 2] = v2;
          rb[wv * 5 + 3] = v3; rb[wv * 5 + 4] = v4;
        }
      }
      __syncthreads();

      if (owner) {
        const float* rb = redB[s & 1];
        float S0 = 0, S1 = 0, S2 = 0, S3 = 0, S4 = 0;
#pragma unroll
        for (int w = 0; w < NOW_O; ++w) {
          S0 += rb[w * 5 + 0]; S1 += rb[w * 5 + 1]; S2 += rb[w * 5 + 2];
          S3 += rb[w * 5 + 3]; S4 += rb[w * 5 + 4];
        }
        float n1 = fmaxf(sqrtf(S1), 1e-6f);
        float n2 = fmaxf(sqrtf(S2), 1e-6f);
        float R = fminf(fmaxf(S0 / (n1 * n2), 0.f), 1.f);
        float a = 1.f - powf(1.f - R, kcur);
        float beta = 1.f - a * a;
        float mu = (beta * Shb + a * S4) * invD;
        float Exx = (beta * beta * Shb2 + 2.f * beta * a * S3 + a * a * S2) * invD;
        float var = Exx - mu * mu;
        float xv = beta * hb + a * ah;
        hsv = fmaxf((xv - mu) * rsqrtf(var + 1e-5f) * g_i + be_i, 0.f);
        hs[tid] = hsv;
        if (s == SETI - 1) hist[(size_t)t * DH + tid] = hsv;
      }
      if (s == SETI - 1) {
        if (tid < t) wlam[tid] *= 0.9f;
        else if (tid == t) wlam[tid] = 0.5f;
        if (tid >= DH && tid < DH + DG / 4)
          ((float4*)zsh)[tid - DH] =
              ((const float4*)(z_seq + ((size_t)(t + 1) * BB + b) * DG))[tid - DH];
      }
      __syncthreads();
    }
  }

  {
    float s1 = 0.f, s2 = 0.f;
    matvec_o<BF16W>(Wh_f, Wg_f, Wh_b, Wg_b,
                    hist + (size_t)(NSTEP - 1) * DH, zsh, bias, hbs,
                    s1, s2, g, lane16, true);
    {
      float v0 = s1, v1 = s2;
#pragma unroll
      for (int off = 32; off; off >>= 1) {
        v0 += __shfl_xor(v0, off, 64);
        v1 += __shfl_xor(v1, off, 64);
      }
      if (lane == 0) { redA[wv * 2] = v0; redA[wv * 2 + 1] = v1; }
    }
    __syncthreads();

    float hb = 0.f, hv = 0.f;
    {
      float S1 = 0.f, S2 = 0.f;
#pragma unroll
      for (int w = 0; w < NW_O; ++w) { S1 += redA[w * 2]; S2 += redA[w * 2 + 1]; }
      Shb = S1; Shb2 = S2;
      if (owner) {
        hb = hbs[tid];
        float m = S1 * invD;
        float var = S2 * invD - m * m;
        hv = fmaxf((hb - m) * rsqrtf(var + 1e-5f) * g_i + be_i, 0.f);
        hs[tid] = hv;
      }
    }
    __syncthreads();

    for (int s = 0; s < SETI; ++s) {
      if (g < NSTEP) {
        const float4* h4 = (const float4*)(hist + (size_t)g * DH);
        const float4* s4 = (const float4*)hs;
        float p = 0.f;
#pragma unroll
        for (int kk = 0; kk < 6; ++kk) {
          float4 hh = h4[lane16 + 16 * kk], ss = s4[lane16 + 16 * kk];
          p = fmaf(hh.x, ss.x, p); p = fmaf(hh.y, ss.y, p);
          p = fmaf(hh.z, ss.z, p); p = fmaf(hh.w, ss.w, p);
        }
        p = group16_reduce(p);
        if (lane16 == 0) carr[g] = p * wlam[g];
      }
      __syncthreads();

      float ah = 0.f;
      if (owner) {
        for (int tau = 0; tau < NSTEP; ++tau)
          ah = fmaf(carr[tau], hist[(size_t)tau * DH + tid], ah);
        float v0 = ah, v1 = ah * ah, v2 = hb * ah;
#pragma unroll
        for (int off = 32; off; off >>= 1) {
          v0 += __shfl_xor(v0, off, 64);
          v1 += __shfl_xor(v1, off, 64);
          v2 += __shfl_xor(v2, off, 64);
        }
        if (lane == 0) {
          float* rb = redB[s & 1];
          rb[wv * 5 + 0] = v0; rb[wv * 5 + 1] = v1; rb[wv * 5 + 2] = v2;
        }
      }
      __syncthreads();

      if (owner) {
        const float* rb = redB[s & 1];
        float S0 = 0, S1 = 0, S2 = 0;
#pragma unroll
        for (int w = 0; w < NOW_O; ++w) {
          S0 += rb[w * 5 + 0]; S1 += rb[w * 5 + 1]; S2 += rb[w * 5 + 2];
        }
        float Sx = Shb + S0;
        float Sxx = Shb2 + 2.f * S2 + S1;
        float mu = Sx * invD;
        float var = Sxx * invD - mu * mu;
        float xv = hb + ah;
        hv = fmaxf((xv - mu) * rsqrtf(var + 1e-5f) * g_i + be_i, 0.f);
        if (s < SETI - 1) hs[tid] = hv;
      }
      if (s < SETI - 1) __syncthreads();
    }

    if (owner) out[(size_t)b * DH + tid] = hv;
  }
}

extern "C" void kernel_launch(void* const* d_in, const int* in_sizes, int n_in,
                              void* d_out, int out_size, void* d_ws, size_t ws_size,
                              hipStream_t stream) {
  const float* z_seq    = (const float*)d_in[0];
  const float* W_h      = (const float*)d_in[1];
  const float* W_g      = (const float*)d_in[2];
  const float* b_h      = (const float*)d_in[3];
  const float* ln_g     = (const float*)d_in[4];
  const float* ln_b     = (const float*)d_in[5];
  const float* alpha_fw = (const float*)d_in[6];
  float* out = (float*)d_out;

  const size_t nWh = (size_t)DH * DH;        // 147456
  const size_t nWg = (size_t)DH * DG;        // 73728
  const size_t nXZ = (size_t)TT * BB * DH;   // 1769472
  const size_t need_fast = nXZ * sizeof(float) + nWh * sizeof(ushort_t);

  if (ws_size >= need_fast) {
    float* XZ = (float*)d_ws;
    ushort_t* Whb = (ushort_t*)((char*)d_ws + nXZ * sizeof(float));
    cvt_kernel<<<dim3((int)((nWh + 255) / 256)), dim3(256), 0, stream>>>(
        W_h, Whb, (int)nWh);
    xz_kernel<<<dim3(TT, BB / 8), dim3(NT_F), 0, stream>>>(z_seq, W_g, b_h, XZ);
    fw_rnn_fast<<<dim3(BB), dim3(NT_F), 0, stream>>>(
        XZ, Whb, ln_g, ln_b, alpha_fw, out);
  } else if (ws_size >= (nWh + nWg) * sizeof(ushort_t)) {
    ushort_t* Whb = (ushort_t*)d_ws;
    ushort_t* Wgb = Whb + nWh;
    cvt_kernel<<<dim3((int)((nWh + 255) / 256)), dim3(256), 0, stream>>>(
        W_h, Whb, (int)nWh);
    cvt_kernel<<<dim3((int)((nWg + 255) / 256)), dim3(256), 0, stream>>>(
        W_g, Wgb, (int)nWg);
    fw_rnn_old<true><<<dim3(BB), dim3(NT_O), 0, stream>>>(
        z_seq, W_h, W_g, Whb, Wgb, b_h, ln_g, ln_b, alpha_fw, out);
  } else {
    fw_rnn_old<false><<<dim3(BB), dim3(NT_O), 0, stream>>>(
        z_seq, W_h, W_g, nullptr, nullptr, b_h, ln_g, ln_b, alpha_fw, out);
  }
}

// Round 5
// 1044.684 us; speedup vs baseline: 1.0874x; 1.0874x over previous
//
#include <hip/hip_runtime.h>
#include <math.h>

// Problem constants
#define TT    48
#define BB    96
#define DG    192
#define DH    384
#define NSTEP 47     // T-1 scan steps
#define SETI  3      // inner settling iterations
#define HP    392    // padded hist row stride (floats)

// fast-kernel config: 768 threads, 48 groups of 16, 8 rows/group
#define NT_F  768
#define NW_F  12
#define NOW_F 6
#define NG_F  48
#define RPG   8      // rows per group (DH / NG_F)

// fallback (round-3) config
#define NT_O  768
#define NW_O  12
#define NOW_O 6
#define NG_O  48

typedef unsigned short ushort_t;

__device__ __forceinline__ float group16_reduce(float v) {
  v += __shfl_xor(v, 8, 64);
  v += __shfl_xor(v, 4, 64);
  v += __shfl_xor(v, 2, 64);
  v += __shfl_xor(v, 1, 64);
  return v;
}

__device__ __forceinline__ float blo(unsigned u) {
  return __uint_as_float(u << 16);
}
__device__ __forceinline__ float bhi(unsigned u) {
  return __uint_as_float(u & 0xFFFF0000u);
}

// ====================== FAST PATH ======================
// W_h resident in VGPRs (bf16, 96 VGPR/thread); W_g*z+b precomputed into XZ.
// __launch_bounds__(768,3): 12-wave block = 3 waves/EU -> VGPR cap ~170,
// enough for Wreg (96) + working set without spilling. 1 block/CU.
__global__ __launch_bounds__(NT_F, 3) void fw_rnn_fast(
    const float* __restrict__ XZ,       // [T*B, DH] = W_g z + b_h
    const ushort_t* __restrict__ Whb,   // [DH, DH] bf16
    const float* __restrict__ ln_g,
    const float* __restrict__ ln_b,
    const float* __restrict__ alpha_fw,
    float* __restrict__ out)            // [B, DH]
{
  __shared__ float hist[NSTEP * HP];
  __shared__ float hs[DH];
  __shared__ float hbs[DH];
  __shared__ float xzs[DH];
  __shared__ float wlam[NSTEP + 1];
  __shared__ float carr[NSTEP + 1];
  __shared__ float redA[NW_F * 2];
  __shared__ float redB[2][NOW_F * 5];

  const int tid    = threadIdx.x;
  const int b      = blockIdx.x;
  const int lane   = tid & 63, wv = tid >> 6;
  const int g      = tid >> 4, lane16 = tid & 15;
  const bool owner = (tid < DH);

  // ---- preload W_h rows into registers: group g owns rows r = p*48+g ----
  uint2 Wreg[RPG][6];
#pragma unroll
  for (int p = 0; p < RPG; ++p) {
    const uint2* wrow = (const uint2*)(Whb + (size_t)(p * NG_F + g) * DH);
#pragma unroll
    for (int c = 0; c < 6; ++c) Wreg[p][c] = wrow[lane16 + 16 * c];
  }

  float g_i = 0.f, be_i = 0.f;
  if (owner) { g_i = ln_g[tid]; be_i = ln_b[tid]; }
  const float af   = alpha_fw[0];
  const float kcur = (af >= 0.f) ? (1.f + log1pf(expf(af)))
                                 : (1.f / (1.f + log1pf(expf(-af))));
  const float invD = 1.0f / (float)DH;

  // stage XZ row for t=0
  if (tid < DH / 4)
    ((float4*)xzs)[tid] = ((const float4*)(XZ + (size_t)b * DH))[tid];
  __syncthreads();

  float Shb = 0.f, Shb2 = 0.f;

  for (int t = 0; t < NSTEP; ++t) {
    // ---------- base: h_base = W_h h_{t-1} + xzs, fused LN stats ----------
    float s1 = 0.f, s2 = 0.f;
    if (t > 0) {
      float4 h[6];
      const float4* h4 = (const float4*)(hist + (size_t)(t - 1) * HP);
#pragma unroll
      for (int c = 0; c < 6; ++c) h[c] = h4[lane16 + 16 * c];
#pragma unroll
      for (int p = 0; p < RPG; ++p) {
        float acc = 0.f;
#pragma unroll
        for (int c = 0; c < 6; ++c) {
          uint2 w = Wreg[p][c];
          acc = fmaf(blo(w.x), h[c].x, acc);
          acc = fmaf(bhi(w.x), h[c].y, acc);
          acc = fmaf(blo(w.y), h[c].z, acc);
          acc = fmaf(bhi(w.y), h[c].w, acc);
        }
        acc = group16_reduce(acc);
        if (lane16 == 0) {
          const int r = p * NG_F + g;
          float v = acc + xzs[r];
          hbs[r] = v;
          s1 += v;
          s2 += v * v;
        }
      }
    } else if (owner) {
      float v = xzs[tid];
      s1 = v;
      s2 = v * v;
    }
    {
      float v0 = s1, v1 = s2;
#pragma unroll
      for (int off = 32; off; off >>= 1) {
        v0 += __shfl_xor(v0, off, 64);
        v1 += __shfl_xor(v1, off, 64);
      }
      if (lane == 0) { redA[wv * 2] = v0; redA[wv * 2 + 1] = v1; }
    }
    __syncthreads();  // (a): hbs + redA visible

    float hb = 0.f, hsv = 0.f;
    {
      float S1 = 0.f, S2 = 0.f;
#pragma unroll
      for (int w = 0; w < NW_F; ++w) { S1 += redA[w * 2]; S2 += redA[w * 2 + 1]; }
      Shb = S1; Shb2 = S2;
      if (owner) {
        hb = (t > 0) ? hbs[tid] : xzs[tid];
        float m   = S1 * invD;
        float var = S2 * invD - m * m;
        hsv = fmaxf((hb - m) * rsqrtf(var + 1e-5f) * g_i + be_i, 0.f);
        hs[tid] = hsv;
      }
    }
    if (t == 0) {
      if (owner) hist[tid] = hsv;
      if (tid == 0) wlam[0] = 0.5f;
      if (tid >= DH && tid < DH + DH / 4)
        ((float4*)xzs)[tid - DH] =
            ((const float4*)(XZ + ((size_t)BB + b) * DH))[tid - DH];
      __syncthreads();
      continue;
    }
    __syncthreads();  // (b): hs visible

    // ---------- settling ----------
    for (int s = 0; s < SETI; ++s) {
      // phase A: d_tau = wlam_tau * (h_tau . h_s); one group per tau
      if (g < t) {
        const float4* hh = (const float4*)(hist + (size_t)g * HP);
        const float4* s4 = (const float4*)hs;
        float p_ = 0.f;
#pragma unroll
        for (int c = 0; c < 6; ++c) {
          float4 x = hh[lane16 + 16 * c], sv = s4[lane16 + 16 * c];
          p_ = fmaf(x.x, sv.x, p_); p_ = fmaf(x.y, sv.y, p_);
          p_ = fmaf(x.z, sv.z, p_); p_ = fmaf(x.w, sv.w, p_);
        }
        p_ = group16_reduce(p_);
        if (lane16 == 0) carr[g] = p_ * wlam[g];
      }
      __syncthreads();  // (i): carr visible

      // phase B: owners compute Ah + 5 partial sums
      float ah = 0.f;
      if (owner) {
        float a0 = 0.f, a1 = 0.f;
        int tau = 0;
        for (; tau + 1 < t; tau += 2) {
          a0 = fmaf(carr[tau], hist[(size_t)tau * HP + tid], a0);
          a1 = fmaf(carr[tau + 1], hist[(size_t)(tau + 1) * HP + tid], a1);
        }
        if (tau < t) a0 = fmaf(carr[tau], hist[(size_t)tau * HP + tid], a0);
        ah = a0 + a1;
        float v0 = hsv * ah, v1 = hsv * hsv, v2 = ah * ah, v3 = hb * ah, v4 = ah;
#pragma unroll
        for (int off = 32; off; off >>= 1) {
          v0 += __shfl_xor(v0, off, 64);
          v1 += __shfl_xor(v1, off, 64);
          v2 += __shfl_xor(v2, off, 64);
          v3 += __shfl_xor(v3, off, 64);
          v4 += __shfl_xor(v4, off, 64);
        }
        if (lane == 0) {
          float* rb = redB[s & 1];
          rb[wv * 5 + 0] = v0; rb[wv * 5 + 1] = v1; rb[wv * 5 + 2] = v2;
          rb[wv * 5 + 3] = v3; rb[wv * 5 + 4] = v4;
        }
      }
      __syncthreads();  // (ii): redB visible

      // phase C: gate + analytic LN + commit
      if (owner) {
        const float* rb = redB[s & 1];
        float S0 = 0, S1 = 0, S2 = 0, S3 = 0, S4 = 0;
#pragma unroll
        for (int w = 0; w < NOW_F; ++w) {
          S0 += rb[w * 5 + 0]; S1 += rb[w * 5 + 1]; S2 += rb[w * 5 + 2];
          S3 += rb[w * 5 + 3]; S4 += rb[w * 5 + 4];
        }
        float n1 = fmaxf(sqrtf(S1), 1e-6f);
        float n2 = fmaxf(sqrtf(S2), 1e-6f);
        float R  = fminf(fmaxf(S0 / (n1 * n2), 0.f), 1.f);
        float a  = 1.f - powf(1.f - R, kcur);
        float beta = 1.f - a * a;
        float mu  = (beta * Shb + a * S4) * invD;
        float Exx = (beta * beta * Shb2 + 2.f * beta * a * S3 + a * a * S2) * invD;
        float var = Exx - mu * mu;
        float xv  = beta * hb + a * ah;
        hsv = fmaxf((xv - mu) * rsqrtf(var + 1e-5f) * g_i + be_i, 0.f);
        hs[tid] = hsv;
        if (s == SETI - 1) hist[(size_t)t * HP + tid] = hsv;
      }
      if (s == SETI - 1) {
        if (tid < t) wlam[tid] *= 0.9f;
        else if (tid == t) wlam[tid] = 0.5f;
        if (tid >= DH && tid < DH + DH / 4)
          ((float4*)xzs)[tid - DH] =
              ((const float4*)(XZ + ((size_t)(t + 1) * BB + b) * DH))[tid - DH];
      }
      __syncthreads();  // (iii)
    }
  }

  // ================= final (query) step =================
  {
    float s1 = 0.f, s2 = 0.f;
    {
      float4 h[6];
      const float4* h4 = (const float4*)(hist + (size_t)(NSTEP - 1) * HP);
#pragma unroll
      for (int c = 0; c < 6; ++c) h[c] = h4[lane16 + 16 * c];
#pragma unroll
      for (int p = 0; p < RPG; ++p) {
        float acc = 0.f;
#pragma unroll
        for (int c = 0; c < 6; ++c) {
          uint2 w = Wreg[p][c];
          acc = fmaf(blo(w.x), h[c].x, acc);
          acc = fmaf(bhi(w.x), h[c].y, acc);
          acc = fmaf(blo(w.y), h[c].z, acc);
          acc = fmaf(bhi(w.y), h[c].w, acc);
        }
        acc = group16_reduce(acc);
        if (lane16 == 0) {
          const int r = p * NG_F + g;
          float v = acc + xzs[r];
          hbs[r] = v;
          s1 += v;
          s2 += v * v;
        }
      }
    }
    {
      float v0 = s1, v1 = s2;
#pragma unroll
      for (int off = 32; off; off >>= 1) {
        v0 += __shfl_xor(v0, off, 64);
        v1 += __shfl_xor(v1, off, 64);
      }
      if (lane == 0) { redA[wv * 2] = v0; redA[wv * 2 + 1] = v1; }
    }
    __syncthreads();

    float hb = 0.f, hv = 0.f;
    {
      float S1 = 0.f, S2 = 0.f;
#pragma unroll
      for (int w = 0; w < NW_F; ++w) { S1 += redA[w * 2]; S2 += redA[w * 2 + 1]; }
      Shb = S1; Shb2 = S2;
      if (owner) {
        hb = hbs[tid];
        float m   = S1 * invD;
        float var = S2 * invD - m * m;
        hv = fmaxf((hb - m) * rsqrtf(var + 1e-5f) * g_i + be_i, 0.f);
        hs[tid] = hv;
      }
    }
    __syncthreads();

    for (int s = 0; s < SETI; ++s) {
      if (g < NSTEP) {
        const float4* hh = (const float4*)(hist + (size_t)g * HP);
        const float4* s4 = (const float4*)hs;
        float p_ = 0.f;
#pragma unroll
        for (int c = 0; c < 6; ++c) {
          float4 x = hh[lane16 + 16 * c], sv = s4[lane16 + 16 * c];
          p_ = fmaf(x.x, sv.x, p_); p_ = fmaf(x.y, sv.y, p_);
          p_ = fmaf(x.z, sv.z, p_); p_ = fmaf(x.w, sv.w, p_);
        }
        p_ = group16_reduce(p_);
        if (lane16 == 0) carr[g] = p_ * wlam[g];
      }
      __syncthreads();

      float ah = 0.f;
      if (owner) {
        float a0 = 0.f, a1 = 0.f;
        int tau = 0;
        for (; tau + 1 < NSTEP; tau += 2) {
          a0 = fmaf(carr[tau], hist[(size_t)tau * HP + tid], a0);
          a1 = fmaf(carr[tau + 1], hist[(size_t)(tau + 1) * HP + tid], a1);
        }
        a0 = fmaf(carr[NSTEP - 1], hist[(size_t)(NSTEP - 1) * HP + tid], a0);
        ah = a0 + a1;
        float v0 = ah, v1 = ah * ah, v2 = hb * ah;
#pragma unroll
        for (int off = 32; off; off >>= 1) {
          v0 += __shfl_xor(v0, off, 64);
          v1 += __shfl_xor(v1, off, 64);
          v2 += __shfl_xor(v2, off, 64);
        }
        if (lane == 0) {
          float* rb = redB[s & 1];
          rb[wv * 5 + 0] = v0; rb[wv * 5 + 1] = v1; rb[wv * 5 + 2] = v2;
        }
      }
      __syncthreads();

      if (owner) {
        const float* rb = redB[s & 1];
        float S0 = 0, S1 = 0, S2 = 0;
#pragma unroll
        for (int w = 0; w < NOW_F; ++w) {
          S0 += rb[w * 5 + 0]; S1 += rb[w * 5 + 1]; S2 += rb[w * 5 + 2];
        }
        float Sx  = Shb + S0;
        float Sxx = Shb2 + 2.f * S2 + S1;
        float mu  = Sx * invD;
        float var = Sxx * invD - mu * mu;
        float xv  = hb + ah;
        hv = fmaxf((xv - mu) * rsqrtf(var + 1e-5f) * g_i + be_i, 0.f);
        if (s < SETI - 1) hs[tid] = hv;
      }
      if (s < SETI - 1) __syncthreads();
    }

    if (owner) out[(size_t)b * DH + tid] = hv;
  }
}

// XZ[t,b,:] = W_g z[t,b] + b_h  — fully parallel precompute (fp32 W_g).
__global__ __launch_bounds__(512) void xz_kernel(
    const float* __restrict__ z_seq, const float* __restrict__ W_g,
    const float* __restrict__ b_h, float* __restrict__ XZ)
{
  __shared__ float zs[8 * DG];
  const int tid = threadIdx.x;
  const int t = blockIdx.x, b0 = blockIdx.y * 8;
  const int g = tid >> 4, lane16 = tid & 15;

  const float4* src = (const float4*)(z_seq + ((size_t)t * BB + b0) * DG);
  if (tid < 8 * DG / 4) ((float4*)zs)[tid] = src[tid];
  __syncthreads();

#pragma unroll 2
  for (int p = 0; p < 12; ++p) {
    const int r = p * 32 + g;
    const float4* wr = (const float4*)(W_g + (size_t)r * DG);
    float4 w[3];
#pragma unroll
    for (int c = 0; c < 3; ++c) w[c] = wr[lane16 + 16 * c];
    float acc[8];
#pragma unroll
    for (int bb = 0; bb < 8; ++bb) acc[bb] = 0.f;
#pragma unroll
    for (int bb = 0; bb < 8; ++bb) {
      const float4* zz = (const float4*)(zs + bb * DG);
#pragma unroll
      for (int c = 0; c < 3; ++c) {
        float4 z = zz[lane16 + 16 * c];
        acc[bb] = fmaf(w[c].x, z.x, acc[bb]);
        acc[bb] = fmaf(w[c].y, z.y, acc[bb]);
        acc[bb] = fmaf(w[c].z, z.z, acc[bb]);
        acc[bb] = fmaf(w[c].w, z.w, acc[bb]);
      }
    }
#pragma unroll
    for (int bb = 0; bb < 8; ++bb) acc[bb] = group16_reduce(acc[bb]);
    if (lane16 == 0) {
      float bh = b_h[r];
#pragma unroll
      for (int bb = 0; bb < 8; ++bb)
        XZ[((size_t)t * BB + b0 + bb) * DH + r] = acc[bb] + bh;
    }
  }
}

// fp32 -> bf16 (RTN-even)
__global__ void cvt_kernel(const float* __restrict__ src,
                           ushort_t* __restrict__ dst, int n) {
  int i = blockIdx.x * blockDim.x + threadIdx.x;
  if (i < n) {
    unsigned u = __float_as_uint(src[i]);
    unsigned r = (u + 0x7FFFu + ((u >> 16) & 1u)) >> 16;
    dst[i] = (ushort_t)r;
  }
}

// ====================== FALLBACK (round-3) ======================
template <bool BF16W>
__device__ __forceinline__ void matvec_o(
    const float* __restrict__ Wh_f, const float* __restrict__ Wg_f,
    const ushort_t* __restrict__ Wh_b, const ushort_t* __restrict__ Wg_b,
    const float* __restrict__ hprev, const float* __restrict__ zsh,
    const float (&bias)[8], float* __restrict__ hbs,
    float& s1, float& s2, int g, int lane16, bool with_h)
{
  const float4* z4 = (const float4*)zsh;
  const float4* h4 = (const float4*)hprev;
#pragma unroll 2
  for (int p = 0; p < 8; ++p) {
    const int r = p * NG_O + g;
    float acc = 0.f;
    if (BF16W) {
      const uint2* wg = (const uint2*)Wg_b + (size_t)r * (DG / 4);
#pragma unroll
      for (int c = 0; c < 3; ++c) {
        uint2 u = wg[lane16 + 16 * c];
        float4 z = z4[lane16 + 16 * c];
        acc = fmaf(blo(u.x), z.x, acc); acc = fmaf(bhi(u.x), z.y, acc);
        acc = fmaf(blo(u.y), z.z, acc); acc = fmaf(bhi(u.y), z.w, acc);
      }
      if (with_h) {
        const uint4* wh = (const uint4*)Wh_b + (size_t)r * (DH / 8);
#pragma unroll
        for (int c = 0; c < 3; ++c) {
          uint4 u = wh[lane16 + 16 * c];
          float4 ha = h4[(lane16 + 16 * c) * 2];
          float4 hb2 = h4[(lane16 + 16 * c) * 2 + 1];
          acc = fmaf(blo(u.x), ha.x, acc);  acc = fmaf(bhi(u.x), ha.y, acc);
          acc = fmaf(blo(u.y), ha.z, acc);  acc = fmaf(bhi(u.y), ha.w, acc);
          acc = fmaf(blo(u.z), hb2.x, acc); acc = fmaf(bhi(u.z), hb2.y, acc);
          acc = fmaf(blo(u.w), hb2.z, acc); acc = fmaf(bhi(u.w), hb2.w, acc);
        }
      }
    } else {
      const float4* wg = (const float4*)Wg_f + (size_t)r * (DG / 4);
#pragma unroll
      for (int c = 0; c < 3; ++c) {
        float4 w = wg[lane16 + 16 * c], z = z4[lane16 + 16 * c];
        acc = fmaf(w.x, z.x, acc); acc = fmaf(w.y, z.y, acc);
        acc = fmaf(w.z, z.z, acc); acc = fmaf(w.w, z.w, acc);
      }
      if (with_h) {
        const float4* wh = (const float4*)Wh_f + (size_t)r * (DH / 4);
#pragma unroll
        for (int c = 0; c < 6; ++c) {
          float4 w = wh[lane16 + 16 * c], h = h4[lane16 + 16 * c];
          acc = fmaf(w.x, h.x, acc); acc = fmaf(w.y, h.y, acc);
          acc = fmaf(w.z, h.z, acc); acc = fmaf(w.w, h.w, acc);
        }
      }
    }
    acc = group16_reduce(acc);
    if (lane16 == 0) {
      float vv = acc + bias[p];
      hbs[r] = vv;
      s1 += vv;
      s2 += vv * vv;
    }
  }
}

template <bool BF16W>
__global__ __launch_bounds__(NT_O) void fw_rnn_old(
    const float* __restrict__ z_seq, const float* __restrict__ Wh_f,
    const float* __restrict__ Wg_f, const ushort_t* __restrict__ Wh_b,
    const ushort_t* __restrict__ Wg_b, const float* __restrict__ b_h,
    const float* __restrict__ ln_g, const float* __restrict__ ln_b,
    const float* __restrict__ alpha_fw, float* __restrict__ out)
{
  __shared__ float hist[NSTEP * DH];
  __shared__ float hs[DH];
  __shared__ float zsh[DG];
  __shared__ float hbs[DH];
  __shared__ float wlam[NSTEP];
  __shared__ float carr[NG_O];
  __shared__ float redA[NW_O * 2];
  __shared__ float redB[2][NOW_O * 5];

  const int tid = threadIdx.x;
  const int b = blockIdx.x;
  const int lane = tid & 63, wv = tid >> 6;
  const int g = tid >> 4, lane16 = tid & 15;
  const bool owner = (tid < DH);

  float bias[8];
#pragma unroll
  for (int p = 0; p < 8; ++p) bias[p] = 0.f;
  if (lane16 == 0) {
#pragma unroll
    for (int p = 0; p < 8; ++p) bias[p] = b_h[p * NG_O + g];
  }
  float g_i = 0.f, be_i = 0.f;
  if (owner) { g_i = ln_g[tid]; be_i = ln_b[tid]; }

  const float af = alpha_fw[0];
  const float kcur = (af >= 0.f) ? (1.f + log1pf(expf(af)))
                                 : (1.f / (1.f + log1pf(expf(-af))));
  const float invD = 1.0f / (float)DH;

  if (tid < DG / 4)
    ((float4*)zsh)[tid] = ((const float4*)(z_seq + (size_t)b * DG))[tid];
  __syncthreads();

  float Shb = 0.f, Shb2 = 0.f;

  for (int t = 0; t < NSTEP; ++t) {
    float s1 = 0.f, s2 = 0.f;
    matvec_o<BF16W>(Wh_f, Wg_f, Wh_b, Wg_b,
                    hist + (size_t)(t > 0 ? t - 1 : 0) * DH, zsh, bias, hbs,
                    s1, s2, g, lane16, t > 0);
    {
      float v0 = s1, v1 = s2;
#pragma unroll
      for (int off = 32; off; off >>= 1) {
        v0 += __shfl_xor(v0, off, 64);
        v1 += __shfl_xor(v1, off, 64);
      }
      if (lane == 0) { redA[wv * 2] = v0; redA[wv * 2 + 1] = v1; }
    }
    __syncthreads();

    float hb = 0.f, hsv = 0.f;
    {
      float S1 = 0.f, S2 = 0.f;
#pragma unroll
      for (int w = 0; w < NW_O; ++w) { S1 += redA[w * 2]; S2 += redA[w * 2 + 1]; }
      Shb = S1; Shb2 = S2;
      if (owner) {
        hb = hbs[tid];
        float m = S1 * invD;
        float var = S2 * invD - m * m;
        hsv = fmaxf((hb - m) * rsqrtf(var + 1e-5f) * g_i + be_i, 0.f);
        hs[tid] = hsv;
      }
    }
    if (t == 0) {
      if (owner) hist[tid] = hsv;
      if (tid == 0) wlam[0] = 0.5f;
      if (tid >= DH && tid < DH + DG / 4)
        ((float4*)zsh)[tid - DH] =
            ((const float4*)(z_seq + ((size_t)1 * BB + b) * DG))[tid - DH];
      __syncthreads();
      continue;
    }
    __syncthreads();

    for (int s = 0; s < SETI; ++s) {
      if (g < t) {
        const float4* h4 = (const float4*)(hist + (size_t)g * DH);
        const float4* s4 = (const float4*)hs;
        float p = 0.f;
#pragma unroll
        for (int kk = 0; kk < 6; ++kk) {
          float4 hh = h4[lane16 + 16 * kk], ss = s4[lane16 + 16 * kk];
          p = fmaf(hh.x, ss.x, p); p = fmaf(hh.y, ss.y, p);
          p = fmaf(hh.z, ss.z, p); p = fmaf(hh.w, ss.w, p);
        }
        p = group16_reduce(p);
        if (lane16 == 0) carr[g] = p * wlam[g];
      }
      __syncthreads();

      float ah = 0.f;
      if (owner) {
        for (int tau = 0; tau < t; ++tau)
          ah = fmaf(carr[tau], hist[(size_t)tau * DH + tid], ah);
        float v0 = hsv * ah, v1 = hsv * hsv, v2 = ah * ah, v3 = hb * ah, v4 = ah;
#pragma unroll
        for (int off = 32; off; off >>= 1) {
          v0 += __shfl_xor(v0, off, 64);
          v1 += __shfl_xor(v1, off, 64);
          v2 += __shfl_xor(v2, off, 64);
          v3 += __shfl_xor(v3, off, 64);
          v4 += __shfl_xor(v4, off, 64);
        }
        if (lane == 0) {
          float* rb = redB[s & 1];
          rb[wv * 5 + 0] = v0; rb[wv * 5 + 1] = v1; rb[wv * 5 + 2] = v2;
          rb[wv * 5 + 3] = v3; rb[wv * 5 + 4] = v4;
        }
      }
      __syncthreads();

      if (owner) {
        const float* rb = redB[s & 1];
        float S0 = 0, S1 = 0, S2 = 0, S3 = 0, S4 = 0;
#pragma unroll
        for (int w = 0; w < NOW_O; ++w) {
          S0 += rb[w * 5 + 0]; S1 += rb[w * 5 + 1]; S2 += rb[w * 5 + 2];
          S3 += rb[w * 5 + 3]; S4 += rb[w * 5 + 4];
        }
        float n1 = fmaxf(sqrtf(S1), 1e-6f);
        float n2 = fmaxf(sqrtf(S2), 1e-6f);
        float R = fminf(fmaxf(S0 / (n1 * n2), 0.f), 1.f);
        float a = 1.f - powf(1.f - R, kcur);
        float beta = 1.f - a * a;
        float mu = (beta * Shb + a * S4) * invD;
        float Exx = (beta * beta * Shb2 + 2.f * beta * a * S3 + a * a * S2) * invD;
        float var = Exx - mu * mu;
        float xv = beta * hb + a * ah;
        hsv = fmaxf((xv - mu) * rsqrtf(var + 1e-5f) * g_i + be_i, 0.f);
        hs[tid] = hsv;
        if (s == SETI - 1) hist[(size_t)t * DH + tid] = hsv;
      }
      if (s == SETI - 1) {
        if (tid < t) wlam[tid] *= 0.9f;
        else if (tid == t) wlam[tid] = 0.5f;
        if (tid >= DH && tid < DH + DG / 4)
          ((float4*)zsh)[tid - DH] =
              ((const float4*)(z_seq + ((size_t)(t + 1) * BB + b) * DG))[tid - DH];
      }
      __syncthreads();
    }
  }

  {
    float s1 = 0.f, s2 = 0.f;
    matvec_o<BF16W>(Wh_f, Wg_f, Wh_b, Wg_b,
                    hist + (size_t)(NSTEP - 1) * DH, zsh, bias, hbs,
                    s1, s2, g, lane16, true);
    {
      float v0 = s1, v1 = s2;
#pragma unroll
      for (int off = 32; off; off >>= 1) {
        v0 += __shfl_xor(v0, off, 64);
        v1 += __shfl_xor(v1, off, 64);
      }
      if (lane == 0) { redA[wv * 2] = v0; redA[wv * 2 + 1] = v1; }
    }
    __syncthreads();

    float hb = 0.f, hv = 0.f;
    {
      float S1 = 0.f, S2 = 0.f;
#pragma unroll
      for (int w = 0; w < NW_O; ++w) { S1 += redA[w * 2]; S2 += redA[w * 2 + 1]; }
      Shb = S1; Shb2 = S2;
      if (owner) {
        hb = hbs[tid];
        float m = S1 * invD;
        float var = S2 * invD - m * m;
        hv = fmaxf((hb - m) * rsqrtf(var + 1e-5f) * g_i + be_i, 0.f);
        hs[tid] = hv;
      }
    }
    __syncthreads();

    for (int s = 0; s < SETI; ++s) {
      if (g < NSTEP) {
        const float4* h4 = (const float4*)(hist + (size_t)g * DH);
        const float4* s4 = (const float4*)hs;
        float p = 0.f;
#pragma unroll
        for (int kk = 0; kk < 6; ++kk) {
          float4 hh = h4[lane16 + 16 * kk], ss = s4[lane16 + 16 * kk];
          p = fmaf(hh.x, ss.x, p); p = fmaf(hh.y, ss.y, p);
          p = fmaf(hh.z, ss.z, p); p = fmaf(hh.w, ss.w, p);
        }
        p = group16_reduce(p);
        if (lane16 == 0) carr[g] = p * wlam[g];
      }
      __syncthreads();

      float ah = 0.f;
      if (owner) {
        for (int tau = 0; tau < NSTEP; ++tau)
          ah = fmaf(carr[tau], hist[(size_t)tau * DH + tid], ah);
        float v0 = ah, v1 = ah * ah, v2 = hb * ah;
#pragma unroll
        for (int off = 32; off; off >>= 1) {
          v0 += __shfl_xor(v0, off, 64);
          v1 += __shfl_xor(v1, off, 64);
          v2 += __shfl_xor(v2, off, 64);
        }
        if (lane == 0) {
          float* rb = redB[s & 1];
          rb[wv * 5 + 0] = v0; rb[wv * 5 + 1] = v1; rb[wv * 5 + 2] = v2;
        }
      }
      __syncthreads();

      if (owner) {
        const float* rb = redB[s & 1];
        float S0 = 0, S1 = 0, S2 = 0;
#pragma unroll
        for (int w = 0; w < NOW_O; ++w) {
          S0 += rb[w * 5 + 0]; S1 += rb[w * 5 + 1]; S2 += rb[w * 5 + 2];
        }
        float Sx = Shb + S0;
        float Sxx = Shb2 + 2.f * S2 + S1;
        float mu = Sx * invD;
        float var = Sxx * invD - mu * mu;
        float xv = hb + ah;
        hv = fmaxf((xv - mu) * rsqrtf(var + 1e-5f) * g_i + be_i, 0.f);
        if (s < SETI - 1) hs[tid] = hv;
      }
      if (s < SETI - 1) __syncthreads();
    }

    if (owner) out[(size_t)b * DH + tid] = hv;
  }
}

extern "C" void kernel_launch(void* const* d_in, const int* in_sizes, int n_in,
                              void* d_out, int out_size, void* d_ws, size_t ws_size,
                              hipStream_t stream) {
  const float* z_seq    = (const float*)d_in[0];
  const float* W_h      = (const float*)d_in[1];
  const float* W_g      = (const float*)d_in[2];
  const float* b_h      = (const float*)d_in[3];
  const float* ln_g     = (const float*)d_in[4];
  const float* ln_b     = (const float*)d_in[5];
  const float* alpha_fw = (const float*)d_in[6];
  float* out = (float*)d_out;

  const size_t nWh = (size_t)DH * DH;        // 147456
  const size_t nWg = (size_t)DH * DG;        // 73728
  const size_t nXZ = (size_t)TT * BB * DH;   // 1769472
  const size_t need_fast = nXZ * sizeof(float) + nWh * sizeof(ushort_t);

  if (ws_size >= need_fast) {
    float* XZ = (float*)d_ws;
    ushort_t* Whb = (ushort_t*)((char*)d_ws + nXZ * sizeof(float));
    cvt_kernel<<<dim3((int)((nWh + 255) / 256)), dim3(256), 0, stream>>>(
        W_h, Whb, (int)nWh);
    xz_kernel<<<dim3(TT, BB / 8), dim3(512), 0, stream>>>(z_seq, W_g, b_h, XZ);
    fw_rnn_fast<<<dim3(BB), dim3(NT_F), 0, stream>>>(
        XZ, Whb, ln_g, ln_b, alpha_fw, out);
  } else if (ws_size >= (nWh + nWg) * sizeof(ushort_t)) {
    ushort_t* Whb = (ushort_t*)d_ws;
    ushort_t* Wgb = Whb + nWh;
    cvt_kernel<<<dim3((int)((nWh + 255) / 256)), dim3(256), 0, stream>>>(
        W_h, Whb, (int)nWh);
    cvt_kernel<<<dim3((int)((nWg + 255) / 256)), dim3(256), 0, stream>>>(
        W_g, Wgb, (int)nWg);
    fw_rnn_old<true><<<dim3(BB), dim3(NT_O), 0, stream>>>(
        z_seq, W_h, W_g, Whb, Wgb, b_h, ln_g, ln_b, alpha_fw, out);
  } else {
    fw_rnn_old<false><<<dim3(BB), dim3(NT_O), 0, stream>>>(
        z_seq, W_h, W_g, nullptr, nullptr, b_h, ln_g, ln_b, alpha_fw, out);
  }
}

// Round 6
// 992.260 us; speedup vs baseline: 1.1448x; 1.0528x over previous
//
#include <hip/hip_runtime.h>
#include <math.h>

// Problem constants
#define TT    48
#define BB    96
#define DG    192
#define DH    384
#define NSTEP 47     // T-1 scan steps
#define SETI  3      // inner settling iterations
#define HP    392    // padded hist row stride (floats)

// fast-kernel config: 768 threads, 48 groups of 16, 8 rows/group
#define NT_F  768
#define NW_F  12
#define NOW_F 6
#define NG_F  48
#define RPG   8      // rows per group (DH / NG_F)

// fallback (round-3) config
#define NT_O  768
#define NW_O  12
#define NOW_O 6
#define NG_O  48

typedef unsigned short ushort_t;

__device__ __forceinline__ float group16_reduce(float v) {
  v += __shfl_xor(v, 8, 64);
  v += __shfl_xor(v, 4, 64);
  v += __shfl_xor(v, 2, 64);
  v += __shfl_xor(v, 1, 64);
  return v;
}

__device__ __forceinline__ float blo(unsigned u) {
  return __uint_as_float(u << 16);
}
__device__ __forceinline__ float bhi(unsigned u) {
  return __uint_as_float(u & 0xFFFF0000u);
}

// ====================== FAST PATH ======================
// W_h resident in VGPRs (bf16, 96 VGPR/thread); W_g*z+b precomputed into XZ.
// amdgpu_waves_per_eu(3,3): 12-wave block, 1 block/CU -> VGPR budget 512/3
// ~= 170. Round-5 evidence: __launch_bounds__(768,3) gave an 84-reg budget
// (2 blocks/CU target) and fully spilled Wreg (WRITE_SIZE 26 MB).
__global__
__attribute__((amdgpu_flat_work_group_size(NT_F, NT_F),
               amdgpu_waves_per_eu(3, 3)))
void fw_rnn_fast(
    const float* __restrict__ XZ,       // [T*B, DH] = W_g z + b_h
    const ushort_t* __restrict__ Whb,   // [DH, DH] bf16
    const float* __restrict__ ln_g,
    const float* __restrict__ ln_b,
    const float* __restrict__ alpha_fw,
    float* __restrict__ out)            // [B, DH]
{
  __shared__ float hist[NSTEP * HP];
  __shared__ float hs[DH];
  __shared__ float hbs[DH];
  __shared__ float xzs[DH];
  __shared__ float wlam[NSTEP + 1];
  __shared__ float carr[NSTEP + 1];
  __shared__ float redA[NW_F * 2];
  __shared__ float redB[2][NOW_F * 5];

  const int tid    = threadIdx.x;
  const int b      = blockIdx.x;
  const int lane   = tid & 63, wv = tid >> 6;
  const int g      = tid >> 4, lane16 = tid & 15;
  const bool owner = (tid < DH);

  // ---- preload W_h rows into registers: group g owns rows r = p*48+g ----
  uint2 Wreg[RPG][6];
#pragma unroll
  for (int p = 0; p < RPG; ++p) {
    const uint2* wrow = (const uint2*)(Whb + (size_t)(p * NG_F + g) * DH);
#pragma unroll
    for (int c = 0; c < 6; ++c) Wreg[p][c] = wrow[lane16 + 16 * c];
  }

  float g_i = 0.f, be_i = 0.f;
  if (owner) { g_i = ln_g[tid]; be_i = ln_b[tid]; }
  const float af   = alpha_fw[0];
  const float kcur = (af >= 0.f) ? (1.f + log1pf(expf(af)))
                                 : (1.f / (1.f + log1pf(expf(-af))));
  const float invD = 1.0f / (float)DH;

  // stage XZ row for t=0
  if (tid < DH / 4)
    ((float4*)xzs)[tid] = ((const float4*)(XZ + (size_t)b * DH))[tid];
  __syncthreads();

  float Shb = 0.f, Shb2 = 0.f;

  for (int t = 0; t < NSTEP; ++t) {
    // ---------- base: h_base = W_h h_{t-1} + xzs, fused LN stats ----------
    float s1 = 0.f, s2 = 0.f;
    if (t > 0) {
      float4 h[6];
      const float4* h4 = (const float4*)(hist + (size_t)(t - 1) * HP);
#pragma unroll
      for (int c = 0; c < 6; ++c) h[c] = h4[lane16 + 16 * c];
#pragma unroll
      for (int p = 0; p < RPG; ++p) {
        float acc = 0.f;
#pragma unroll
        for (int c = 0; c < 6; ++c) {
          uint2 w = Wreg[p][c];
          acc = fmaf(blo(w.x), h[c].x, acc);
          acc = fmaf(bhi(w.x), h[c].y, acc);
          acc = fmaf(blo(w.y), h[c].z, acc);
          acc = fmaf(bhi(w.y), h[c].w, acc);
        }
        acc = group16_reduce(acc);
        if (lane16 == 0) {
          const int r = p * NG_F + g;
          float v = acc + xzs[r];
          hbs[r] = v;
          s1 += v;
          s2 += v * v;
        }
      }
    } else if (owner) {
      float v = xzs[tid];
      s1 = v;
      s2 = v * v;
    }
    {
      float v0 = s1, v1 = s2;
#pragma unroll
      for (int off = 32; off; off >>= 1) {
        v0 += __shfl_xor(v0, off, 64);
        v1 += __shfl_xor(v1, off, 64);
      }
      if (lane == 0) { redA[wv * 2] = v0; redA[wv * 2 + 1] = v1; }
    }
    __syncthreads();  // (a): hbs + redA visible

    float hb = 0.f, hsv = 0.f;
    {
      float S1 = 0.f, S2 = 0.f;
#pragma unroll
      for (int w = 0; w < NW_F; ++w) { S1 += redA[w * 2]; S2 += redA[w * 2 + 1]; }
      Shb = S1; Shb2 = S2;
      if (owner) {
        hb = (t > 0) ? hbs[tid] : xzs[tid];
        float m   = S1 * invD;
        float var = S2 * invD - m * m;
        hsv = fmaxf((hb - m) * rsqrtf(var + 1e-5f) * g_i + be_i, 0.f);
        hs[tid] = hsv;
      }
    }
    if (t == 0) {
      if (owner) hist[tid] = hsv;
      if (tid == 0) wlam[0] = 0.5f;
      if (tid >= DH && tid < DH + DH / 4)
        ((float4*)xzs)[tid - DH] =
            ((const float4*)(XZ + ((size_t)BB + b) * DH))[tid - DH];
      __syncthreads();
      continue;
    }
    __syncthreads();  // (b): hs visible

    // ---------- settling ----------
    for (int s = 0; s < SETI; ++s) {
      // phase A: d_tau = wlam_tau * (h_tau . h_s); one group per tau
      if (g < t) {
        const float4* hh = (const float4*)(hist + (size_t)g * HP);
        const float4* s4 = (const float4*)hs;
        float p_ = 0.f;
#pragma unroll
        for (int c = 0; c < 6; ++c) {
          float4 x = hh[lane16 + 16 * c], sv = s4[lane16 + 16 * c];
          p_ = fmaf(x.x, sv.x, p_); p_ = fmaf(x.y, sv.y, p_);
          p_ = fmaf(x.z, sv.z, p_); p_ = fmaf(x.w, sv.w, p_);
        }
        p_ = group16_reduce(p_);
        if (lane16 == 0) carr[g] = p_ * wlam[g];
      }
      __syncthreads();  // (i): carr visible

      // phase B: owners compute Ah + 5 partial sums
      float ah = 0.f;
      if (owner) {
        float a0 = 0.f, a1 = 0.f;
        int tau = 0;
        for (; tau + 1 < t; tau += 2) {
          a0 = fmaf(carr[tau], hist[(size_t)tau * HP + tid], a0);
          a1 = fmaf(carr[tau + 1], hist[(size_t)(tau + 1) * HP + tid], a1);
        }
        if (tau < t) a0 = fmaf(carr[tau], hist[(size_t)tau * HP + tid], a0);
        ah = a0 + a1;
        float v0 = hsv * ah, v1 = hsv * hsv, v2 = ah * ah, v3 = hb * ah, v4 = ah;
#pragma unroll
        for (int off = 32; off; off >>= 1) {
          v0 += __shfl_xor(v0, off, 64);
          v1 += __shfl_xor(v1, off, 64);
          v2 += __shfl_xor(v2, off, 64);
          v3 += __shfl_xor(v3, off, 64);
          v4 += __shfl_xor(v4, off, 64);
        }
        if (lane == 0) {
          float* rb = redB[s & 1];
          rb[wv * 5 + 0] = v0; rb[wv * 5 + 1] = v1; rb[wv * 5 + 2] = v2;
          rb[wv * 5 + 3] = v3; rb[wv * 5 + 4] = v4;
        }
      }
      __syncthreads();  // (ii): redB visible

      // phase C: gate + analytic LN + commit
      if (owner) {
        const float* rb = redB[s & 1];
        float S0 = 0, S1 = 0, S2 = 0, S3 = 0, S4 = 0;
#pragma unroll
        for (int w = 0; w < NOW_F; ++w) {
          S0 += rb[w * 5 + 0]; S1 += rb[w * 5 + 1]; S2 += rb[w * 5 + 2];
          S3 += rb[w * 5 + 3]; S4 += rb[w * 5 + 4];
        }
        float n1 = fmaxf(sqrtf(S1), 1e-6f);
        float n2 = fmaxf(sqrtf(S2), 1e-6f);
        float R  = fminf(fmaxf(S0 / (n1 * n2), 0.f), 1.f);
        float a  = 1.f - powf(1.f - R, kcur);
        float beta = 1.f - a * a;
        float mu  = (beta * Shb + a * S4) * invD;
        float Exx = (beta * beta * Shb2 + 2.f * beta * a * S3 + a * a * S2) * invD;
        float var = Exx - mu * mu;
        float xv  = beta * hb + a * ah;
        hsv = fmaxf((xv - mu) * rsqrtf(var + 1e-5f) * g_i + be_i, 0.f);
        hs[tid] = hsv;
        if (s == SETI - 1) hist[(size_t)t * HP + tid] = hsv;
      }
      if (s == SETI - 1) {
        if (tid < t) wlam[tid] *= 0.9f;
        else if (tid == t) wlam[tid] = 0.5f;
        if (tid >= DH && tid < DH + DH / 4)
          ((float4*)xzs)[tid - DH] =
              ((const float4*)(XZ + ((size_t)(t + 1) * BB + b) * DH))[tid - DH];
      }
      __syncthreads();  // (iii)
    }
  }

  // ================= final (query) step =================
  {
    float s1 = 0.f, s2 = 0.f;
    {
      float4 h[6];
      const float4* h4 = (const float4*)(hist + (size_t)(NSTEP - 1) * HP);
#pragma unroll
      for (int c = 0; c < 6; ++c) h[c] = h4[lane16 + 16 * c];
#pragma unroll
      for (int p = 0; p < RPG; ++p) {
        float acc = 0.f;
#pragma unroll
        for (int c = 0; c < 6; ++c) {
          uint2 w = Wreg[p][c];
          acc = fmaf(blo(w.x), h[c].x, acc);
          acc = fmaf(bhi(w.x), h[c].y, acc);
          acc = fmaf(blo(w.y), h[c].z, acc);
          acc = fmaf(bhi(w.y), h[c].w, acc);
        }
        acc = group16_reduce(acc);
        if (lane16 == 0) {
          const int r = p * NG_F + g;
          float v = acc + xzs[r];
          hbs[r] = v;
          s1 += v;
          s2 += v * v;
        }
      }
    }
    {
      float v0 = s1, v1 = s2;
#pragma unroll
      for (int off = 32; off; off >>= 1) {
        v0 += __shfl_xor(v0, off, 64);
        v1 += __shfl_xor(v1, off, 64);
      }
      if (lane == 0) { redA[wv * 2] = v0; redA[wv * 2 + 1] = v1; }
    }
    __syncthreads();

    float hb = 0.f, hv = 0.f;
    {
      float S1 = 0.f, S2 = 0.f;
#pragma unroll
      for (int w = 0; w < NW_F; ++w) { S1 += redA[w * 2]; S2 += redA[w * 2 + 1]; }
      Shb = S1; Shb2 = S2;
      if (owner) {
        hb = hbs[tid];
        float m   = S1 * invD;
        float var = S2 * invD - m * m;
        hv = fmaxf((hb - m) * rsqrtf(var + 1e-5f) * g_i + be_i, 0.f);
        hs[tid] = hv;
      }
    }
    __syncthreads();

    for (int s = 0; s < SETI; ++s) {
      if (g < NSTEP) {
        const float4* hh = (const float4*)(hist + (size_t)g * HP);
        const float4* s4 = (const float4*)hs;
        float p_ = 0.f;
#pragma unroll
        for (int c = 0; c < 6; ++c) {
          float4 x = hh[lane16 + 16 * c], sv = s4[lane16 + 16 * c];
          p_ = fmaf(x.x, sv.x, p_); p_ = fmaf(x.y, sv.y, p_);
          p_ = fmaf(x.z, sv.z, p_); p_ = fmaf(x.w, sv.w, p_);
        }
        p_ = group16_reduce(p_);
        if (lane16 == 0) carr[g] = p_ * wlam[g];
      }
      __syncthreads();

      float ah = 0.f;
      if (owner) {
        float a0 = 0.f, a1 = 0.f;
        int tau = 0;
        for (; tau + 1 < NSTEP; tau += 2) {
          a0 = fmaf(carr[tau], hist[(size_t)tau * HP + tid], a0);
          a1 = fmaf(carr[tau + 1], hist[(size_t)(tau + 1) * HP + tid], a1);
        }
        a0 = fmaf(carr[NSTEP - 1], hist[(size_t)(NSTEP - 1) * HP + tid], a0);
        ah = a0 + a1;
        float v0 = ah, v1 = ah * ah, v2 = hb * ah;
#pragma unroll
        for (int off = 32; off; off >>= 1) {
          v0 += __shfl_xor(v0, off, 64);
          v1 += __shfl_xor(v1, off, 64);
          v2 += __shfl_xor(v2, off, 64);
        }
        if (lane == 0) {
          float* rb = redB[s & 1];
          rb[wv * 5 + 0] = v0; rb[wv * 5 + 1] = v1; rb[wv * 5 + 2] = v2;
        }
      }
      __syncthreads();

      if (owner) {
        const float* rb = redB[s & 1];
        float S0 = 0, S1 = 0, S2 = 0;
#pragma unroll
        for (int w = 0; w < NOW_F; ++w) {
          S0 += rb[w * 5 + 0]; S1 += rb[w * 5 + 1]; S2 += rb[w * 5 + 2];
        }
        float Sx  = Shb + S0;
        float Sxx = Shb2 + 2.f * S2 + S1;
        float mu  = Sx * invD;
        float var = Sxx * invD - mu * mu;
        float xv  = hb + ah;
        hv = fmaxf((xv - mu) * rsqrtf(var + 1e-5f) * g_i + be_i, 0.f);
        if (s < SETI - 1) hs[tid] = hv;
      }
      if (s < SETI - 1) __syncthreads();
    }

    if (owner) out[(size_t)b * DH + tid] = hv;
  }
}

// XZ[t,b,:] = W_g z[t,b] + b_h  — fully parallel precompute (fp32 W_g).
__global__ __launch_bounds__(512) void xz_kernel(
    const float* __restrict__ z_seq, const float* __restrict__ W_g,
    const float* __restrict__ b_h, float* __restrict__ XZ)
{
  __shared__ float zs[8 * DG];
  const int tid = threadIdx.x;
  const int t = blockIdx.x, b0 = blockIdx.y * 8;
  const int g = tid >> 4, lane16 = tid & 15;

  const float4* src = (const float4*)(z_seq + ((size_t)t * BB + b0) * DG);
  if (tid < 8 * DG / 4) ((float4*)zs)[tid] = src[tid];
  __syncthreads();

#pragma unroll 2
  for (int p = 0; p < 12; ++p) {
    const int r = p * 32 + g;
    const float4* wr = (const float4*)(W_g + (size_t)r * DG);
    float4 w[3];
#pragma unroll
    for (int c = 0; c < 3; ++c) w[c] = wr[lane16 + 16 * c];
    float acc[8];
#pragma unroll
    for (int bb = 0; bb < 8; ++bb) acc[bb] = 0.f;
#pragma unroll
    for (int bb = 0; bb < 8; ++bb) {
      const float4* zz = (const float4*)(zs + bb * DG);
#pragma unroll
      for (int c = 0; c < 3; ++c) {
        float4 z = zz[lane16 + 16 * c];
        acc[bb] = fmaf(w[c].x, z.x, acc[bb]);
        acc[bb] = fmaf(w[c].y, z.y, acc[bb]);
        acc[bb] = fmaf(w[c].z, z.z, acc[bb]);
        acc[bb] = fmaf(w[c].w, z.w, acc[bb]);
      }
    }
#pragma unroll
    for (int bb = 0; bb < 8; ++bb) acc[bb] = group16_reduce(acc[bb]);
    if (lane16 == 0) {
      float bh = b_h[r];
#pragma unroll
      for (int bb = 0; bb < 8; ++bb)
        XZ[((size_t)t * BB + b0 + bb) * DH + r] = acc[bb] + bh;
    }
  }
}

// fp32 -> bf16 (RTN-even)
__global__ void cvt_kernel(const float* __restrict__ src,
                           ushort_t* __restrict__ dst, int n) {
  int i = blockIdx.x * blockDim.x + threadIdx.x;
  if (i < n) {
    unsigned u = __float_as_uint(src[i]);
    unsigned r = (u + 0x7FFFu + ((u >> 16) & 1u)) >> 16;
    dst[i] = (ushort_t)r;
  }
}

// ====================== FALLBACK (round-3) ======================
template <bool BF16W>
__device__ __forceinline__ void matvec_o(
    const float* __restrict__ Wh_f, const float* __restrict__ Wg_f,
    const ushort_t* __restrict__ Wh_b, const ushort_t* __restrict__ Wg_b,
    const float* __restrict__ hprev, const float* __restrict__ zsh,
    const float (&bias)[8], float* __restrict__ hbs,
    float& s1, float& s2, int g, int lane16, bool with_h)
{
  const float4* z4 = (const float4*)zsh;
  const float4* h4 = (const float4*)hprev;
#pragma unroll 2
  for (int p = 0; p < 8; ++p) {
    const int r = p * NG_O + g;
    float acc = 0.f;
    if (BF16W) {
      const uint2* wg = (const uint2*)Wg_b + (size_t)r * (DG / 4);
#pragma unroll
      for (int c = 0; c < 3; ++c) {
        uint2 u = wg[lane16 + 16 * c];
        float4 z = z4[lane16 + 16 * c];
        acc = fmaf(blo(u.x), z.x, acc); acc = fmaf(bhi(u.x), z.y, acc);
        acc = fmaf(blo(u.y), z.z, acc); acc = fmaf(bhi(u.y), z.w, acc);
      }
      if (with_h) {
        const uint4* wh = (const uint4*)Wh_b + (size_t)r * (DH / 8);
#pragma unroll
        for (int c = 0; c < 3; ++c) {
          uint4 u = wh[lane16 + 16 * c];
          float4 ha = h4[(lane16 + 16 * c) * 2];
          float4 hb2 = h4[(lane16 + 16 * c) * 2 + 1];
          acc = fmaf(blo(u.x), ha.x, acc);  acc = fmaf(bhi(u.x), ha.y, acc);
          acc = fmaf(blo(u.y), ha.z, acc);  acc = fmaf(bhi(u.y), ha.w, acc);
          acc = fmaf(blo(u.z), hb2.x, acc); acc = fmaf(bhi(u.z), hb2.y, acc);
          acc = fmaf(blo(u.w), hb2.z, acc); acc = fmaf(bhi(u.w), hb2.w, acc);
        }
      }
    } else {
      const float4* wg = (const float4*)Wg_f + (size_t)r * (DG / 4);
#pragma unroll
      for (int c = 0; c < 3; ++c) {
        float4 w = wg[lane16 + 16 * c], z = z4[lane16 + 16 * c];
        acc = fmaf(w.x, z.x, acc); acc = fmaf(w.y, z.y, acc);
        acc = fmaf(w.z, z.z, acc); acc = fmaf(w.w, z.w, acc);
      }
      if (with_h) {
        const float4* wh = (const float4*)Wh_f + (size_t)r * (DH / 4);
#pragma unroll
        for (int c = 0; c < 6; ++c) {
          float4 w = wh[lane16 + 16 * c], h = h4[lane16 + 16 * c];
          acc = fmaf(w.x, h.x, acc); acc = fmaf(w.y, h.y, acc);
          acc = fmaf(w.z, h.z, acc); acc = fmaf(w.w, h.w, acc);
        }
      }
    }
    acc = group16_reduce(acc);
    if (lane16 == 0) {
      float vv = acc + bias[p];
      hbs[r] = vv;
      s1 += vv;
      s2 += vv * vv;
    }
  }
}

template <bool BF16W>
__global__ __launch_bounds__(NT_O) void fw_rnn_old(
    const float* __restrict__ z_seq, const float* __restrict__ Wh_f,
    const float* __restrict__ Wg_f, const ushort_t* __restrict__ Wh_b,
    const ushort_t* __restrict__ Wg_b, const float* __restrict__ b_h,
    const float* __restrict__ ln_g, const float* __restrict__ ln_b,
    const float* __restrict__ alpha_fw, float* __restrict__ out)
{
  __shared__ float hist[NSTEP * DH];
  __shared__ float hs[DH];
  __shared__ float zsh[DG];
  __shared__ float hbs[DH];
  __shared__ float wlam[NSTEP];
  __shared__ float carr[NG_O];
  __shared__ float redA[NW_O * 2];
  __shared__ float redB[2][NOW_O * 5];

  const int tid = threadIdx.x;
  const int b = blockIdx.x;
  const int lane = tid & 63, wv = tid >> 6;
  const int g = tid >> 4, lane16 = tid & 15;
  const bool owner = (tid < DH);

  float bias[8];
#pragma unroll
  for (int p = 0; p < 8; ++p) bias[p] = 0.f;
  if (lane16 == 0) {
#pragma unroll
    for (int p = 0; p < 8; ++p) bias[p] = b_h[p * NG_O + g];
  }
  float g_i = 0.f, be_i = 0.f;
  if (owner) { g_i = ln_g[tid]; be_i = ln_b[tid]; }

  const float af = alpha_fw[0];
  const float kcur = (af >= 0.f) ? (1.f + log1pf(expf(af)))
                                 : (1.f / (1.f + log1pf(expf(-af))));
  const float invD = 1.0f / (float)DH;

  if (tid < DG / 4)
    ((float4*)zsh)[tid] = ((const float4*)(z_seq + (size_t)b * DG))[tid];
  __syncthreads();

  float Shb = 0.f, Shb2 = 0.f;

  for (int t = 0; t < NSTEP; ++t) {
    float s1 = 0.f, s2 = 0.f;
    matvec_o<BF16W>(Wh_f, Wg_f, Wh_b, Wg_b,
                    hist + (size_t)(t > 0 ? t - 1 : 0) * DH, zsh, bias, hbs,
                    s1, s2, g, lane16, t > 0);
    {
      float v0 = s1, v1 = s2;
#pragma unroll
      for (int off = 32; off; off >>= 1) {
        v0 += __shfl_xor(v0, off, 64);
        v1 += __shfl_xor(v1, off, 64);
      }
      if (lane == 0) { redA[wv * 2] = v0; redA[wv * 2 + 1] = v1; }
    }
    __syncthreads();

    float hb = 0.f, hsv = 0.f;
    {
      float S1 = 0.f, S2 = 0.f;
#pragma unroll
      for (int w = 0; w < NW_O; ++w) { S1 += redA[w * 2]; S2 += redA[w * 2 + 1]; }
      Shb = S1; Shb2 = S2;
      if (owner) {
        hb = hbs[tid];
        float m = S1 * invD;
        float var = S2 * invD - m * m;
        hsv = fmaxf((hb - m) * rsqrtf(var + 1e-5f) * g_i + be_i, 0.f);
        hs[tid] = hsv;
      }
    }
    if (t == 0) {
      if (owner) hist[tid] = hsv;
      if (tid == 0) wlam[0] = 0.5f;
      if (tid >= DH && tid < DH + DG / 4)
        ((float4*)zsh)[tid - DH] =
            ((const float4*)(z_seq + ((size_t)1 * BB + b) * DG))[tid - DH];
      __syncthreads();
      continue;
    }
    __syncthreads();

    for (int s = 0; s < SETI; ++s) {
      if (g < t) {
        const float4* h4 = (const float4*)(hist + (size_t)g * DH);
        const float4* s4 = (const float4*)hs;
        float p = 0.f;
#pragma unroll
        for (int kk = 0; kk < 6; ++kk) {
          float4 hh = h4[lane16 + 16 * kk], ss = s4[lane16 + 16 * kk];
          p = fmaf(hh.x, ss.x, p); p = fmaf(hh.y, ss.y, p);
          p = fmaf(hh.z, ss.z, p); p = fmaf(hh.w, ss.w, p);
        }
        p = group16_reduce(p);
        if (lane16 == 0) carr[g] = p * wlam[g];
      }
      __syncthreads();

      float ah = 0.f;
      if (owner) {
        for (int tau = 0; tau < t; ++tau)
          ah = fmaf(carr[tau], hist[(size_t)tau * DH + tid], ah);
        float v0 = hsv * ah, v1 = hsv * hsv, v2 = ah * ah, v3 = hb * ah, v4 = ah;
#pragma unroll
        for (int off = 32; off; off >>= 1) {
          v0 += __shfl_xor(v0, off, 64);
          v1 += __shfl_xor(v1, off, 64);
          v2 += __shfl_xor(v2, off, 64);
          v3 += __shfl_xor(v3, off, 64);
          v4 += __shfl_xor(v4, off, 64);
        }
        if (lane == 0) {
          float* rb = redB[s & 1];
          rb[wv * 5 + 0] = v0; rb[wv * 5 + 1] = v1; rb[wv * 5 + 2] = v2;
          rb[wv * 5 + 3] = v3; rb[wv * 5 + 4] = v4;
        }
      }
      __syncthreads();

      if (owner) {
        const float* rb = redB[s & 1];
        float S0 = 0, S1 = 0, S2 = 0, S3 = 0, S4 = 0;
#pragma unroll
        for (int w = 0; w < NOW_O; ++w) {
          S0 += rb[w * 5 + 0]; S1 += rb[w * 5 + 1]; S2 += rb[w * 5 + 2];
          S3 += rb[w * 5 + 3]; S4 += rb[w * 5 + 4];
        }
        float n1 = fmaxf(sqrtf(S1), 1e-6f);
        float n2 = fmaxf(sqrtf(S2), 1e-6f);
        float R = fminf(fmaxf(S0 / (n1 * n2), 0.f), 1.f);
        float a = 1.f - powf(1.f - R, kcur);
        float beta = 1.f - a * a;
        float mu = (beta * Shb + a * S4) * invD;
        float Exx = (beta * beta * Shb2 + 2.f * beta * a * S3 + a * a * S2) * invD;
        float var = Exx - mu * mu;
        float xv = beta * hb + a * ah;
        hsv = fmaxf((xv - mu) * rsqrtf(var + 1e-5f) * g_i + be_i, 0.f);
        hs[tid] = hsv;
        if (s == SETI - 1) hist[(size_t)t * DH + tid] = hsv;
      }
      if (s == SETI - 1) {
        if (tid < t) wlam[tid] *= 0.9f;
        else if (tid == t) wlam[tid] = 0.5f;
        if (tid >= DH && tid < DH + DG / 4)
          ((float4*)zsh)[tid - DH] =
              ((const float4*)(z_seq + ((size_t)(t + 1) * BB + b) * DG))[tid - DH];
      }
      __syncthreads();
    }
  }

  {
    float s1 = 0.f, s2 = 0.f;
    matvec_o<BF16W>(Wh_f, Wg_f, Wh_b, Wg_b,
                    hist + (size_t)(NSTEP - 1) * DH, zsh, bias, hbs,
                    s1, s2, g, lane16, true);
    {
      float v0 = s1, v1 = s2;
#pragma unroll
      for (int off = 32; off; off >>= 1) {
        v0 += __shfl_xor(v0, off, 64);
        v1 += __shfl_xor(v1, off, 64);
      }
      if (lane == 0) { redA[wv * 2] = v0; redA[wv * 2 + 1] = v1; }
    }
    __syncthreads();

    float hb = 0.f, hv = 0.f;
    {
      float S1 = 0.f, S2 = 0.f;
#pragma unroll
      for (int w = 0; w < NW_O; ++w) { S1 += redA[w * 2]; S2 += redA[w * 2 + 1]; }
      Shb = S1; Shb2 = S2;
      if (owner) {
        hb = hbs[tid];
        float m = S1 * invD;
        float var = S2 * invD - m * m;
        hv = fmaxf((hb - m) * rsqrtf(var + 1e-5f) * g_i + be_i, 0.f);
        hs[tid] = hv;
      }
    }
    __syncthreads();

    for (int s = 0; s < SETI; ++s) {
      if (g < NSTEP) {
        const float4* h4 = (const float4*)(hist + (size_t)g * DH);
        const float4* s4 = (const float4*)hs;
        float p = 0.f;
#pragma unroll
        for (int kk = 0; kk < 6; ++kk) {
          float4 hh = h4[lane16 + 16 * kk], ss = s4[lane16 + 16 * kk];
          p = fmaf(hh.x, ss.x, p); p = fmaf(hh.y, ss.y, p);
          p = fmaf(hh.z, ss.z, p); p = fmaf(hh.w, ss.w, p);
        }
        p = group16_reduce(p);
        if (lane16 == 0) carr[g] = p * wlam[g];
      }
      __syncthreads();

      float ah = 0.f;
      if (owner) {
        for (int tau = 0; tau < NSTEP; ++tau)
          ah = fmaf(carr[tau], hist[(size_t)tau * DH + tid], ah);
        float v0 = ah, v1 = ah * ah, v2 = hb * ah;
#pragma unroll
        for (int off = 32; off; off >>= 1) {
          v0 += __shfl_xor(v0, off, 64);
          v1 += __shfl_xor(v1, off, 64);
          v2 += __shfl_xor(v2, off, 64);
        }
        if (lane == 0) {
          float* rb = redB[s & 1];
          rb[wv * 5 + 0] = v0; rb[wv * 5 + 1] = v1; rb[wv * 5 + 2] = v2;
        }
      }
      __syncthreads();

      if (owner) {
        const float* rb = redB[s & 1];
        float S0 = 0, S1 = 0, S2 = 0;
#pragma unroll
        for (int w = 0; w < NOW_O; ++w) {
          S0 += rb[w * 5 + 0]; S1 += rb[w * 5 + 1]; S2 += rb[w * 5 + 2];
        }
        float Sx = Shb + S0;
        float Sxx = Shb2 + 2.f * S2 + S1;
        float mu = Sx * invD;
        float var = Sxx * invD - mu * mu;
        float xv = hb + ah;
        hv = fmaxf((xv - mu) * rsqrtf(var + 1e-5f) * g_i + be_i, 0.f);
        if (s < SETI - 1) hs[tid] = hv;
      }
      if (s < SETI - 1) __syncthreads();
    }

    if (owner) out[(size_t)b * DH + tid] = hv;
  }
}

extern "C" void kernel_launch(void* const* d_in, const int* in_sizes, int n_in,
                              void* d_out, int out_size, void* d_ws, size_t ws_size,
                              hipStream_t stream) {
  const float* z_seq    = (const float*)d_in[0];
  const float* W_h      = (const float*)d_in[1];
  const float* W_g      = (const float*)d_in[2];
  const float* b_h      = (const float*)d_in[3];
  const float* ln_g     = (const float*)d_in[4];
  const float* ln_b     = (const float*)d_in[5];
  const float* alpha_fw = (const float*)d_in[6];
  float* out = (float*)d_out;

  const size_t nWh = (size_t)DH * DH;        // 147456
  const size_t nWg = (size_t)DH * DG;        // 73728
  const size_t nXZ = (size_t)TT * BB * DH;   // 1769472
  const size_t need_fast = nXZ * sizeof(float) + nWh * sizeof(ushort_t);

  if (ws_size >= need_fast) {
    float* XZ = (float*)d_ws;
    ushort_t* Whb = (ushort_t*)((char*)d_ws + nXZ * sizeof(float));
    cvt_kernel<<<dim3((int)((nWh + 255) / 256)), dim3(256), 0, stream>>>(
        W_h, Whb, (int)nWh);
    xz_kernel<<<dim3(TT, BB / 8), dim3(512), 0, stream>>>(z_seq, W_g, b_h, XZ);
    fw_rnn_fast<<<dim3(BB), dim3(NT_F), 0, stream>>>(
        XZ, Whb, ln_g, ln_b, alpha_fw, out);
  } else if (ws_size >= (nWh + nWg) * sizeof(ushort_t)) {
    ushort_t* Whb = (ushort_t*)d_ws;
    ushort_t* Wgb = Whb + nWh;
    cvt_kernel<<<dim3((int)((nWh + 255) / 256)), dim3(256), 0, stream>>>(
        W_h, Whb, (int)nWh);
    cvt_kernel<<<dim3((int)((nWg + 255) / 256)), dim3(256), 0, stream>>>(
        W_g, Wgb, (int)nWg);
    fw_rnn_old<true><<<dim3(BB), dim3(NT_O), 0, stream>>>(
        z_seq, W_h, W_g, Whb, Wgb, b_h, ln_g, ln_b, alpha_fw, out);
  } else {
    fw_rnn_old<false><<<dim3(BB), dim3(NT_O), 0, stream>>>(
        z_seq, W_h, W_g, nullptr, nullptr, b_h, ln_g, ln_b, alpha_fw, out);
  }
}